// Round 1
// baseline (3686.608 us; speedup 1.0000x reference)
//
#include <hip/hip_runtime.h>

#define BB 64
#define LL 32
#define DD 512
#define HH 1024
#define GG 4096   // 4*H
#define VV 32000
#define EHH 512
#define ELL 40

// ws layout (float units)
#define OFF_H   0                        // hstates: [33][64][1024]  (index 0 = hx0)
#define OFF_C   (33*BB*HH)               // cx: [64][1024]
#define OFF_GX  (OFF_C + BB*HH)          // gates_x: [32][64][4096]
#define OFF_AM  (OFF_GX + LL*BB*GG)      // amax: 2048 u64 (=4096 floats)

__device__ __forceinline__ unsigned long long packkey(float v, int n) {
    unsigned u = __float_as_uint(v);
    u = (u & 0x80000000u) ? ~u : (u | 0x80000000u);
    return ((unsigned long long)u << 32) | (unsigned)(0x7FFFFFFF - n);
}

// ---- hx0 = hidden_state[:, -1, :] @ W_p.T + b_p ; cx = 0 ; amax = 0 ----
__global__ __launch_bounds__(128) void init_kernel(
    const float* __restrict__ hid, const float* __restrict__ Wp,
    const float* __restrict__ bp, float* __restrict__ h0,
    float* __restrict__ cx, unsigned long long* __restrict__ amax)
{
    int b = blockIdx.x;
    int h = blockIdx.y * 128 + threadIdx.x;
    const float4* hrow = (const float4*)(hid + ((size_t)b*ELL + (ELL-1))*EHH);
    const float4* wrow = (const float4*)(Wp + (size_t)h*EHH);
    float acc = 0.f;
    #pragma unroll 4
    for (int k = 0; k < EHH/4; ++k) {
        float4 a = hrow[k], w = wrow[k];
        acc += a.x*w.x + a.y*w.y + a.z*w.z + a.w*w.w;
    }
    h0[b*HH + h] = acc + bp[h];
    cx[b*HH + h] = 0.f;
    int tg = (b*8 + blockIdx.y)*128 + threadIdx.x;
    if (tg < LL*BB) amax[tg] = 0ULL;
}

// ---- gates_x[l*64+b][g] = sent[b][l][:] . W_ih[g][:] + b_ih[g] + b_hh[g] ----
#define KT 16
__global__ __launch_bounds__(256) void gates_x_kernel(
    const float* __restrict__ x, const float* __restrict__ Wih,
    const float* __restrict__ bih, const float* __restrict__ bhh,
    float* __restrict__ gx)
{
    __shared__ float As[KT][68];
    __shared__ float Bs[KT][68];
    const int l  = blockIdx.x;        // M-tile = one l, rows b=0..63
    const int n0 = blockIdx.y * 64;
    const int tid = threadIdx.x;
    const int tx = tid & 15, ty = tid >> 4;
    float acc[4][4] = {};
    for (int k0 = 0; k0 < DD; k0 += KT) {
        int i = tid * 4;
        int m = i >> 4, kk = i & 15;
        float4 a = *(const float4*)(x + ((size_t)m*LL + l)*DD + k0 + kk);
        As[kk+0][m]=a.x; As[kk+1][m]=a.y; As[kk+2][m]=a.z; As[kk+3][m]=a.w;
        float4 w = *(const float4*)(Wih + (size_t)(n0+m)*DD + k0 + kk);
        Bs[kk+0][m]=w.x; Bs[kk+1][m]=w.y; Bs[kk+2][m]=w.z; Bs[kk+3][m]=w.w;
        __syncthreads();
        #pragma unroll
        for (int k = 0; k < KT; ++k) {
            float4 av = *(const float4*)&As[k][ty*4];
            float4 bv = *(const float4*)&Bs[k][tx*4];
            float aa[4] = {av.x,av.y,av.z,av.w};
            float bb2[4] = {bv.x,bv.y,bv.z,bv.w};
            #pragma unroll
            for (int i2 = 0; i2 < 4; ++i2)
                #pragma unroll
                for (int j = 0; j < 4; ++j)
                    acc[i2][j] += aa[i2]*bb2[j];
        }
        __syncthreads();
    }
    #pragma unroll
    for (int i2 = 0; i2 < 4; ++i2) {
        int m = ty*4 + i2;
        int r = l*64 + m;
        int n = n0 + tx*4;
        float4 o;
        o.x = acc[i2][0] + bih[n+0] + bhh[n+0];
        o.y = acc[i2][1] + bih[n+1] + bhh[n+1];
        o.z = acc[i2][2] + bih[n+2] + bhh[n+2];
        o.w = acc[i2][3] + bih[n+3] + bhh[n+3];
        *(float4*)(gx + (size_t)r*GG + n) = o;
    }
}

// ---- one recurrence step: gates = gx + hprev @ W_hh.T ; LSTM cell ----
#define KT2 32
__global__ __launch_bounds__(256) void lstm_step_kernel(
    const float* __restrict__ gx,    // [64][4096] for this step (pre-biased)
    const float* __restrict__ Whh,   // [4096][1024]
    const float* __restrict__ hprev, // [64][1024]
    float* __restrict__ hnew,        // [64][1024]
    float* __restrict__ cx)          // [64][1024] in-out
{
    __shared__ float Hs[16][KT2+4];
    __shared__ float Ws[64][KT2+4];
    const int hb = blockIdx.x;   // 0..63
    const int bg = blockIdx.y;   // 0..3
    const int tid = threadIdx.x;
    const int hi = tid & 15, bi = tid >> 4;
    const int b = bg*16 + bi;
    const int h = hb*16 + hi;
    float acc[4] = {0.f,0.f,0.f,0.f};
    for (int k0 = 0; k0 < HH; k0 += KT2) {
        {
            int i = tid * 2;
            int row = i >> 5, kk = i & 31;
            *(float2*)&Hs[row][kk] = *(const float2*)(hprev + (size_t)(bg*16+row)*HH + k0 + kk);
            int wrow = tid >> 2;
            int wkk  = (tid & 3) * 8;
            int g_ = wrow >> 4, hr = wrow & 15;
            const float* src = Whh + ((size_t)g_*HH + hb*16 + hr)*HH + k0 + wkk;
            *(float4*)&Ws[wrow][wkk]   = *(const float4*)(src);
            *(float4*)&Ws[wrow][wkk+4] = *(const float4*)(src+4);
        }
        __syncthreads();
        #pragma unroll
        for (int kk = 0; kk < KT2; kk += 4) {
            float4 hv = *(const float4*)&Hs[bi][kk];
            #pragma unroll
            for (int g_ = 0; g_ < 4; ++g_) {
                float4 wv = *(const float4*)&Ws[g_*16 + hi][kk];
                acc[g_] += hv.x*wv.x + hv.y*wv.y + hv.z*wv.z + hv.w*wv.w;
            }
        }
        __syncthreads();
    }
    const float* gxr = gx + (size_t)b*GG;
    float gi = acc[0] + gxr[0*HH + h];
    float gf = acc[1] + gxr[1*HH + h];
    float gg = acc[2] + gxr[2*HH + h];
    float go = acc[3] + gxr[3*HH + h];
    float si = 1.f/(1.f + expf(-gi));
    float sf = 1.f/(1.f + expf(-gf));
    float so = 1.f/(1.f + expf(-go));
    float cc = cx[b*HH + h];
    float cn = sf*cc + si*tanhf(gg);
    float hn = so*tanhf(cn);
    cx[b*HH + h] = cn;
    hnew[b*HH + h] = hn;
}

// ---- logits = hs_all @ W_v.T + b_v, fused argmax ----
__global__ __launch_bounds__(256) void logits_kernel(
    const float* __restrict__ A,   // [2048][1024] (hstates rows 64..)
    const float* __restrict__ Wv,  // [32000][1024]
    const float* __restrict__ bv,
    float* __restrict__ out,       // [64][32][32000]
    unsigned long long* __restrict__ amax)
{
    __shared__ float As[KT][68];
    __shared__ float Bs[KT][68];
    __shared__ unsigned long long red[64][17];
    const int m0 = blockIdx.x * 64;
    const int n0 = blockIdx.y * 64;
    const int tid = threadIdx.x;
    const int tx = tid & 15, ty = tid >> 4;
    float acc[4][4] = {};
    for (int k0 = 0; k0 < HH; k0 += KT) {
        int i = tid * 4;
        int m = i >> 4, kk = i & 15;
        float4 a = *(const float4*)(A + (size_t)(m0+m)*HH + k0 + kk);
        As[kk+0][m]=a.x; As[kk+1][m]=a.y; As[kk+2][m]=a.z; As[kk+3][m]=a.w;
        float4 w = *(const float4*)(Wv + (size_t)(n0+m)*HH + k0 + kk);
        Bs[kk+0][m]=w.x; Bs[kk+1][m]=w.y; Bs[kk+2][m]=w.z; Bs[kk+3][m]=w.w;
        __syncthreads();
        #pragma unroll
        for (int k = 0; k < KT; ++k) {
            float4 av = *(const float4*)&As[k][ty*4];
            float4 bv4 = *(const float4*)&Bs[k][tx*4];
            float aa[4] = {av.x,av.y,av.z,av.w};
            float bb2[4] = {bv4.x,bv4.y,bv4.z,bv4.w};
            #pragma unroll
            for (int i2 = 0; i2 < 4; ++i2)
                #pragma unroll
                for (int j = 0; j < 4; ++j)
                    acc[i2][j] += aa[i2]*bb2[j];
        }
        __syncthreads();
    }
    #pragma unroll
    for (int i2 = 0; i2 < 4; ++i2) {
        int m = ty*4 + i2;
        int r = m0 + m;
        int b = r & 63, l = r >> 6;
        int n = n0 + tx*4;
        float4 o;
        o.x = acc[i2][0] + bv[n+0];
        o.y = acc[i2][1] + bv[n+1];
        o.z = acc[i2][2] + bv[n+2];
        o.w = acc[i2][3] + bv[n+3];
        *(float4*)(out + ((size_t)(b*LL + l))*VV + n) = o;
        unsigned long long best = packkey(o.x, n);
        unsigned long long k1 = packkey(o.y, n+1); if (k1 > best) best = k1;
        k1 = packkey(o.z, n+2); if (k1 > best) best = k1;
        k1 = packkey(o.w, n+3); if (k1 > best) best = k1;
        red[m][tx] = best;
    }
    __syncthreads();
    if (tid < 64) {
        unsigned long long bb2 = red[tid][0];
        #pragma unroll
        for (int j = 1; j < 16; ++j) { unsigned long long v = red[tid][j]; if (v > bb2) bb2 = v; }
        atomicMax(&amax[m0 + tid], bb2);
    }
}

__global__ __launch_bounds__(256) void finalize_kernel(
    const unsigned long long* __restrict__ amax, float* __restrict__ outp)
{
    int r = blockIdx.x * 256 + threadIdx.x;
    if (r < LL*BB) {
        unsigned n = 0x7FFFFFFFu - (unsigned)(amax[r] & 0xFFFFFFFFu);
        int b = r & 63, l = r >> 6;
        outp[b*LL + l] = (float)n;
    }
}

extern "C" void kernel_launch(void* const* d_in, const int* in_sizes, int n_in,
                              void* d_out, int out_size, void* d_ws, size_t ws_size,
                              hipStream_t stream) {
    (void)in_sizes; (void)n_in; (void)out_size; (void)ws_size;
    const float* sent = (const float*)d_in[0];
    const float* hid  = (const float*)d_in[1];
    const float* Wih  = (const float*)d_in[2];
    const float* Whh  = (const float*)d_in[3];
    const float* bih  = (const float*)d_in[4];
    const float* bhh  = (const float*)d_in[5];
    const float* Wp   = (const float*)d_in[6];
    const float* bp   = (const float*)d_in[7];
    const float* Wv   = (const float*)d_in[8];
    const float* bv   = (const float*)d_in[9];
    float* out = (float*)d_out;

    float* ws = (float*)d_ws;
    float* hst = ws + OFF_H;                 // [33][64][1024]
    float* cx  = ws + OFF_C;
    float* gx  = ws + OFF_GX;                // [32][64][4096]
    unsigned long long* amax = (unsigned long long*)(ws + OFF_AM);

    init_kernel<<<dim3(BB, 8), 128, 0, stream>>>(hid, Wp, bp, hst, cx, amax);
    gates_x_kernel<<<dim3(LL, GG/64), 256, 0, stream>>>(sent, Wih, bih, bhh, gx);
    for (int s = 1; s <= LL; ++s) {
        lstm_step_kernel<<<dim3(64, 4), 256, 0, stream>>>(
            gx + (size_t)(s-1)*BB*GG, Whh,
            hst + (size_t)(s-1)*BB*HH, hst + (size_t)s*BB*HH, cx);
    }
    logits_kernel<<<dim3(2048/64, VV/64), 256, 0, stream>>>(
        hst + (size_t)BB*HH, Wv, bv, out, amax);
    finalize_kernel<<<dim3((LL*BB + 255)/256), 256, 0, stream>>>(
        amax, out + (size_t)BB*LL*VV);
}